// Round 1
// baseline (160.731 us; speedup 1.0000x reference)
//
#include <hip/hip_runtime.h>
#include <math.h>

#define NH 49152
#define KI 1024
#define DD 32
#define HF 256

// ws layout (float indices)
#define WS_PART   0                 // [0]=vrep [1]=vatt [2]=noise_sum [3]=n_noise(uint) [4]=sum(1-beta_a)
#define WS_SEGMAX 8                 // KI floats
#define WS_ALPHA  (WS_SEGMAX + KI)  // KI ints
#define WS_QA     (WS_ALPHA + KI)   // KI floats
#define WS_CA     (WS_QA + KI)      // KI floats
#define WS_XA     (WS_CA + KI)      // KI*DD floats
#define WS_Q      (WS_XA + KI*DD)   // NH floats
#define WS_BC     (WS_Q + NH)       // NH floats
#define WS_OX     (WS_BC + NH)      // NH*DD floats

__global__ void k_init(float* __restrict__ ws) {
    int i = blockIdx.x * blockDim.x + threadIdx.x;
    if (i < KI) {
        ws[WS_SEGMAX + i] = 0.0f;
        ((int*)ws)[WS_ALPHA + i] = NH;
    }
    if (i < 8) ws[WS_PART + i] = 0.0f;
}

__global__ __launch_bounds__(256) void k_gemm(
        const float* __restrict__ x, const float* __restrict__ Wb,
        const float* __restrict__ bb, const float* __restrict__ Wc,
        const float* __restrict__ bcrd, const int* __restrict__ yi,
        float* __restrict__ ws) {
    __shared__ float xs[64 * 65];   // 64 hits x 64 k, pad to 65
    __shared__ float wl[64 * 36];   // 64 k x 33 cols, pad to 36
    const int t  = threadIdx.x;
    const int hl = t & 63;          // hit within tile
    const int g  = t >> 6;          // output-col group (wave id)
    const int h0 = blockIdx.x * 64;

    float acc0 = 0.f, acc1 = 0.f, acc2 = 0.f, acc3 = 0.f;
    float acc4 = 0.f, acc5 = 0.f, acc6 = 0.f, acc7 = 0.f, acc8 = 0.f;

    for (int kc = 0; kc < 4; ++kc) {
        // stage x tile [64 hits][64 k], coalesced float4 loads
        for (int i = 0; i < 4; ++i) {
            int f = i * 256 + t;
            int row = f >> 4, c4 = f & 15;
            const float4 v = *(const float4*)(x + (size_t)(h0 + row) * HF + kc * 64 + c4 * 4);
            float* dst = xs + row * 65 + c4 * 4;
            dst[0] = v.x; dst[1] = v.y; dst[2] = v.z; dst[3] = v.w;
        }
        // stage W tile [64 k][33]
        for (int idx = t; idx < 64 * 33; idx += 256) {
            int kk = idx / 33;
            int c  = idx - kk * 33;
            int kg = kc * 64 + kk;
            wl[kk * 36 + c] = (c < 32) ? Wc[kg * 32 + c] : Wb[kg];
        }
        __syncthreads();
        #pragma unroll 8
        for (int kk = 0; kk < 64; ++kk) {
            float a = xs[hl * 65 + kk];
            const float4 w0 = *(const float4*)(wl + kk * 36 + g * 8);
            const float4 w1 = *(const float4*)(wl + kk * 36 + g * 8 + 4);
            acc0 = fmaf(a, w0.x, acc0);
            acc1 = fmaf(a, w0.y, acc1);
            acc2 = fmaf(a, w0.z, acc2);
            acc3 = fmaf(a, w0.w, acc3);
            acc4 = fmaf(a, w1.x, acc4);
            acc5 = fmaf(a, w1.y, acc5);
            acc6 = fmaf(a, w1.z, acc6);
            acc7 = fmaf(a, w1.w, acc7);
            if (g == 3) acc8 = fmaf(a, wl[kk * 36 + 32], acc8);
        }
        __syncthreads();
    }

    const int h = h0 + hl;
    float4 o0, o1;
    o0.x = acc0 + bcrd[g * 8 + 0];
    o0.y = acc1 + bcrd[g * 8 + 1];
    o0.z = acc2 + bcrd[g * 8 + 2];
    o0.w = acc3 + bcrd[g * 8 + 3];
    o1.x = acc4 + bcrd[g * 8 + 4];
    o1.y = acc5 + bcrd[g * 8 + 5];
    o1.z = acc6 + bcrd[g * 8 + 6];
    o1.w = acc7 + bcrd[g * 8 + 7];
    *(float4*)(ws + WS_OX + (size_t)h * DD + g * 8)     = o0;
    *(float4*)(ws + WS_OX + (size_t)h * DD + g * 8 + 4) = o1;

    if (g == 3) {
        float z    = acc8 + bb[0];
        float beta = 1.0f / (1.0f + expf(-z));
        float bcv  = fminf(fmaxf(beta, 1e-4f), 0.9999f);
        float at   = atanhf(bcv);
        ws[WS_Q + h]  = at * at + 0.5f;
        ws[WS_BC + h] = bcv;
        int y = yi[h];
        float    nb  = (y < 0) ? bcv : 0.0f;
        unsigned cnt = (y < 0) ? 1u : 0u;
        for (int off = 32; off > 0; off >>= 1) {
            nb  += __shfl_down(nb, off);
            cnt += __shfl_down(cnt, off);
        }
        if (hl == 0) {
            atomicAdd(ws + WS_PART + 2, nb);
            atomicAdd((unsigned int*)(ws + WS_PART + 3), cnt);
        }
    }
}

__global__ __launch_bounds__(256) void k_segmax(const int* __restrict__ eh, const int* __restrict__ ei,
                                                int E, float* __restrict__ ws) {
    int e = blockIdx.x * 256 + threadIdx.x;
    if (e < E) {
        float qe = ws[WS_Q + eh[e]];
        atomicMax((unsigned int*)(ws + WS_SEGMAX + ei[e]), __float_as_uint(qe));
    }
}

__global__ __launch_bounds__(256) void k_argmin(const int* __restrict__ eh, const int* __restrict__ ei,
                                                int E, float* __restrict__ ws) {
    int e = blockIdx.x * 256 + threadIdx.x;
    if (e < E) {
        float qe = ws[WS_Q + eh[e]];
        if (qe >= ws[WS_SEGMAX + ei[e]])
            atomicMin((int*)ws + WS_ALPHA + ei[e], eh[e]);
    }
}

__global__ __launch_bounds__(1024) void k_gather(float* __restrict__ ws) {
    const int k = threadIdx.x;
    int a = ((int*)ws)[WS_ALPHA + k];
    a = min(a, NH - 1);
    float s8 = 0.0f;
    #pragma unroll
    for (int d0 = 0; d0 < DD; d0 += 4) {
        float4 v = *(const float4*)(ws + WS_OX + (size_t)a * DD + d0);
        *(float4*)(ws + WS_XA + (size_t)k * DD + d0) = v;
        if (d0 < 8) s8 += v.x * v.x + v.y * v.y + v.z * v.z + v.w * v.w;
    }
    ws[WS_CA + k] = 0.5f * (s8 - 1.0f);
    ws[WS_QA + k] = ws[WS_Q + a];
    float omba = 1.0f - ws[WS_BC + a];
    for (int off = 32; off > 0; off >>= 1) omba += __shfl_down(omba, off);
    __shared__ float red[16];
    if ((k & 63) == 0) red[k >> 6] = omba;
    __syncthreads();
    if (k == 0) {
        float s = 0.0f;
        for (int i = 0; i < 16; ++i) s += red[i];
        atomicAdd(ws + WS_PART + 4, s);
    }
}

__global__ __launch_bounds__(256) void k_att(const int* __restrict__ eh, const int* __restrict__ ei,
                                             int E, float* __restrict__ ws) {
    const int t = threadIdx.x;
    const int e = blockIdx.x * 256 + t;
    float c = 0.0f;
    if (e < E) {
        const int h = eh[e], k = ei[e];
        const float* a = ws + WS_OX + (size_t)h * DD;
        const float* b = ws + WS_XA + (size_t)k * DD;
        float d2 = 0.0f;
        #pragma unroll
        for (int d0 = 0; d0 < DD; d0 += 4) {
            float4 av = *(const float4*)(a + d0);
            float4 bv = *(const float4*)(b + d0);
            float dx = av.x - bv.x; d2 = fmaf(dx, dx, d2);
            float dy = av.y - bv.y; d2 = fmaf(dy, dy, d2);
            float dz = av.z - bv.z; d2 = fmaf(dz, dz, d2);
            float dw = av.w - bv.w; d2 = fmaf(dw, dw, d2);
        }
        c = ws[WS_Q + h] * ws[WS_QA + k] * d2;
    }
    for (int off = 32; off > 0; off >>= 1) c += __shfl_down(c, off);
    __shared__ float red[4];
    if ((t & 63) == 0) red[t >> 6] = c;
    __syncthreads();
    if (t == 0) atomicAdd(ws + WS_PART + 1, red[0] + red[1] + red[2] + red[3]);
}

// v_rep: N x K pairs, exact 8-dim lower-bound filter, full path only on candidates
__global__ __launch_bounds__(64) void k_rep(const int* __restrict__ yi, float* __restrict__ ws) {
    __shared__ float xa8[256 * 8];
    __shared__ float cal[256];
    __shared__ float qal[256];
    const int t  = threadIdx.x;
    const int bk = blockIdx.x & 3;       // k-chunk
    const int bh = blockIdx.x >> 2;      // hit tile
    const int k0 = bk * 256;

    #pragma unroll
    for (int i = 0; i < 8; ++i) {
        int f = i * 64 + t;
        int r = f >> 1, half = f & 1;
        float4 v = *(const float4*)(ws + WS_XA + (size_t)(k0 + r) * DD + half * 4);
        *(float4*)(xa8 + r * 8 + half * 4) = v;
    }
    #pragma unroll
    for (int i = 0; i < 4; ++i) {
        int j = i * 64 + t;
        cal[j] = ws[WS_CA + k0 + j];
        qal[j] = ws[WS_QA + k0 + j];
    }
    __syncthreads();

    const int h = bh * 64 + t;
    const float4 a0 = *(const float4*)(ws + WS_OX + (size_t)h * DD);
    const float4 a1 = *(const float4*)(ws + WS_OX + (size_t)h * DD + 4);
    float s8 = a0.x * a0.x + a0.y * a0.y + a0.z * a0.z + a0.w * a0.w
             + a1.x * a1.x + a1.y * a1.y + a1.z * a1.z + a1.w * a1.w;
    const float ch = 0.5f * s8;
    const float qh = ws[WS_Q + h];
    const int   yh = yi[h];
    float local = 0.0f;

    #pragma unroll 4
    for (int r = 0; r < 256; ++r) {
        const float4 b0 = *(const float4*)(xa8 + r * 8);
        const float4 b1 = *(const float4*)(xa8 + r * 8 + 4);
        float acc = -ch - cal[r];
        acc = fmaf(a0.x, b0.x, acc);
        acc = fmaf(a0.y, b0.y, acc);
        acc = fmaf(a0.z, b0.z, acc);
        acc = fmaf(a0.w, b0.w, acc);
        acc = fmaf(a1.x, b1.x, acc);
        acc = fmaf(a1.y, b1.y, acc);
        acc = fmaf(a1.z, b1.z, acc);
        acc = fmaf(a1.w, b1.w, acc);
        // acc > 0  <=>  d2 over first 8 dims < 1  (exact lower bound on full d2)
        if (acc > 0.0f) {
            const int kg = k0 + r;
            if (yh != kg) {
                float d2 = 1.0f - 2.0f * acc;   // exact d2 over first 8 dims
                for (int d0 = 8; d0 < DD; d0 += 4) {
                    float4 av = *(const float4*)(ws + WS_OX + (size_t)h * DD + d0);
                    float4 bv = *(const float4*)(ws + WS_XA + (size_t)kg * DD + d0);
                    float dx = av.x - bv.x; d2 = fmaf(dx, dx, d2);
                    float dy = av.y - bv.y; d2 = fmaf(dy, dy, d2);
                    float dz = av.z - bv.z; d2 = fmaf(dz, dz, d2);
                    float dw = av.w - bv.w; d2 = fmaf(dw, dw, d2);
                }
                float dist = sqrtf(fmaxf(d2, 0.0f) + 1e-12f);
                float hin = 1.0f - dist;
                if (hin > 0.0f) local += qh * qal[r] * hin;
            }
        }
    }
    for (int off = 32; off > 0; off >>= 1) local += __shfl_down(local, off);
    if (t == 0) atomicAdd(ws + WS_PART + 0, local);
}

__global__ void k_final(const float* __restrict__ temp, float* __restrict__ ws,
                        float* __restrict__ out) {
    float vrep  = ws[WS_PART + 0];
    float vatt  = ws[WS_PART + 1];
    float nsum  = ws[WS_PART + 2];
    unsigned nn = *(const unsigned int*)(ws + WS_PART + 3);
    float somba = ws[WS_PART + 4];
    float lb = somba * (1.0f / (float)KI) + nsum / (float)(nn < 1u ? 1u : nn);
    float lv = (vatt + vrep) / (float)NH;
    float tv = temp[0];
    out[0] = (lb + lv) * expf(-tv) + tv;
}

extern "C" void kernel_launch(void* const* d_in, const int* in_sizes, int n_in,
                              void* d_out, int out_size, void* d_ws, size_t ws_size,
                              hipStream_t stream) {
    const float* x    = (const float*)d_in[0];
    const float* Wb   = (const float*)d_in[1];
    const float* bb   = (const float*)d_in[2];
    const float* Wc   = (const float*)d_in[3];
    const float* bcrd = (const float*)d_in[4];
    const float* temp = (const float*)d_in[5];
    const int*   yi   = (const int*)d_in[6];
    const int*   ep   = (const int*)d_in[8];
    const int E = in_sizes[8] / 2;
    const int* eh = ep;
    const int* ei = ep + E;
    float* ws  = (float*)d_ws;
    float* out = (float*)d_out;

    k_init<<<(KI + 255) / 256, 256, 0, stream>>>(ws);
    k_gemm<<<NH / 64, 256, 0, stream>>>(x, Wb, bb, Wc, bcrd, yi, ws);
    const int eb = (E + 255) / 256;
    k_segmax<<<eb, 256, 0, stream>>>(eh, ei, E, ws);
    k_argmin<<<eb, 256, 0, stream>>>(eh, ei, E, ws);
    k_gather<<<1, 1024, 0, stream>>>(ws);
    k_att<<<eb, 256, 0, stream>>>(eh, ei, E, ws);
    k_rep<<<(NH / 64) * 4, 64, 0, stream>>>(yi, ws);
    k_final<<<1, 1, 0, stream>>>(temp, ws, out);
}

// Round 2
// 117.655 us; speedup vs baseline: 1.3661x; 1.3661x over previous
//
#include <hip/hip_runtime.h>
#include <math.h>

#define NH 49152
#define KI 1024
#define DD 32
#define HF 256

// ws layout (float indices)
// PART: [0]=vrep [1]=vatt [2]=noise_sum [3]=n_noise(uint) [4]=sum(1-beta_a)
#define WS_PART   0
#define WS_SEGMAX 8
#define WS_ALPHA  (WS_SEGMAX + KI)       // KI ints
#define WS_XA     (WS_ALPHA + KI)        // KI*DD floats (full alpha coords)
#define WS_A12    (WS_XA + KI*DD)        // KI*12: d0..7, ca, qa, pad2
#define WS_H12    (WS_A12 + KI*12)       // NH*12: d0..7, ch, qh, bc, pad
#define WS_OX     (WS_H12 + NH*12)       // NH*DD floats

__global__ void k_init(float* __restrict__ ws) {
    int i = blockIdx.x * blockDim.x + threadIdx.x;
    if (i < KI) {
        ws[WS_SEGMAX + i] = 0.0f;
        ((int*)ws)[WS_ALPHA + i] = NH;
    }
    if (i < 8) ws[WS_PART + i] = 0.0f;
}

// 64 hits x 33 cols per block; W staged ONCE (broadcast reads), x prefetched
// (T14 async split: issue loads for chunk c+1 before computing chunk c).
__global__ __launch_bounds__(256, 2) void k_gemm(
        const float* __restrict__ x, const float* __restrict__ Wb,
        const float* __restrict__ bb, const float* __restrict__ Wc,
        const float* __restrict__ bcrd, const int* __restrict__ yi,
        float* __restrict__ ws) {
    __shared__ float wl[256 * 36];   // [k][36]: cols 0..31 = Wc, 32 = Wb
    __shared__ float xs[64 * 65];    // [hit][65] pad -> conflict-free b32 reads
    const int t  = threadIdx.x;
    const int hl = t & 63;
    const int g  = t >> 6;
    const int h0 = blockIdx.x * 64;

    // stage full W: thread t stages k-row t
    #pragma unroll
    for (int c4 = 0; c4 < 8; ++c4)
        *(float4*)(wl + t * 36 + c4 * 4) = *(const float4*)(Wc + t * 32 + c4 * 4);
    wl[t * 36 + 32] = Wb[t];

    const int srow = t >> 4;         // 0..15
    const int scol = (t & 15) * 4;   // 0..60
    float4 r0, r1, r2, r3;
#define LOADC(kc) { \
        const float* xp = x + (size_t)(h0 + srow) * HF + (kc) * 64 + scol; \
        r0 = *(const float4*)(xp); \
        r1 = *(const float4*)(xp + 16 * HF); \
        r2 = *(const float4*)(xp + 32 * HF); \
        r3 = *(const float4*)(xp + 48 * HF); }
#define STOREC() { \
        float* d0p = xs + srow * 65 + scol; \
        d0p[0]=r0.x; d0p[1]=r0.y; d0p[2]=r0.z; d0p[3]=r0.w; \
        float* d1p = xs + (srow+16) * 65 + scol; \
        d1p[0]=r1.x; d1p[1]=r1.y; d1p[2]=r1.z; d1p[3]=r1.w; \
        float* d2p = xs + (srow+32) * 65 + scol; \
        d2p[0]=r2.x; d2p[1]=r2.y; d2p[2]=r2.z; d2p[3]=r2.w; \
        float* d3p = xs + (srow+48) * 65 + scol; \
        d3p[0]=r3.x; d3p[1]=r3.y; d3p[2]=r3.z; d3p[3]=r3.w; }

    float acc0 = 0.f, acc1 = 0.f, acc2 = 0.f, acc3 = 0.f;
    float acc4 = 0.f, acc5 = 0.f, acc6 = 0.f, acc7 = 0.f, acc8 = 0.f;

    LOADC(0);
    __syncthreads();   // W staged
    STOREC();
    __syncthreads();   // xs chunk 0 ready

    for (int kc = 0; kc < 4; ++kc) {
        if (kc < 3) LOADC(kc + 1);            // async: latency hides under compute
        const float* wbase = wl + kc * 64 * 36 + g * 8;
        #pragma unroll 8
        for (int kk = 0; kk < 64; ++kk) {
            float a = xs[hl * 65 + kk];
            const float4 w0 = *(const float4*)(wbase + kk * 36);
            const float4 w1 = *(const float4*)(wbase + kk * 36 + 4);
            acc0 = fmaf(a, w0.x, acc0);
            acc1 = fmaf(a, w0.y, acc1);
            acc2 = fmaf(a, w0.z, acc2);
            acc3 = fmaf(a, w0.w, acc3);
            acc4 = fmaf(a, w1.x, acc4);
            acc5 = fmaf(a, w1.y, acc5);
            acc6 = fmaf(a, w1.z, acc6);
            acc7 = fmaf(a, w1.w, acc7);
            if (g == 3) acc8 = fmaf(a, wbase[kk * 36 + 8], acc8);  // col 32
        }
        __syncthreads();                      // all reads of xs done
        if (kc < 3) { STOREC(); __syncthreads(); }
    }

    const int h = h0 + hl;
    float4 o0, o1;
    o0.x = acc0 + bcrd[g * 8 + 0];
    o0.y = acc1 + bcrd[g * 8 + 1];
    o0.z = acc2 + bcrd[g * 8 + 2];
    o0.w = acc3 + bcrd[g * 8 + 3];
    o1.x = acc4 + bcrd[g * 8 + 4];
    o1.y = acc5 + bcrd[g * 8 + 5];
    o1.z = acc6 + bcrd[g * 8 + 6];
    o1.w = acc7 + bcrd[g * 8 + 7];
    *(float4*)(ws + WS_OX + (size_t)h * DD + g * 8)     = o0;
    *(float4*)(ws + WS_OX + (size_t)h * DD + g * 8 + 4) = o1;

    if (g == 0) {   // packed filter record: dims 0..7 + ch
        float s8 = o0.x*o0.x + o0.y*o0.y + o0.z*o0.z + o0.w*o0.w
                 + o1.x*o1.x + o1.y*o1.y + o1.z*o1.z + o1.w*o1.w;
        *(float4*)(ws + WS_H12 + (size_t)h * 12)     = o0;
        *(float4*)(ws + WS_H12 + (size_t)h * 12 + 4) = o1;
        ws[WS_H12 + (size_t)h * 12 + 8] = 0.5f * s8;
    }
    if (g == 3) {
        float z    = acc8 + bb[0];
        float beta = 1.0f / (1.0f + expf(-z));
        float bcv  = fminf(fmaxf(beta, 1e-4f), 0.9999f);
        float at   = atanhf(bcv);
        ws[WS_H12 + (size_t)h * 12 + 9]  = at * at + 0.5f;   // q
        ws[WS_H12 + (size_t)h * 12 + 10] = bcv;              // beta_c
        int y = yi[h];
        float    nb  = (y < 0) ? bcv : 0.0f;
        unsigned cnt = (y < 0) ? 1u : 0u;
        for (int off = 32; off > 0; off >>= 1) {
            nb  += __shfl_down(nb, off);
            cnt += __shfl_down(cnt, off);
        }
        if (hl == 0) {
            atomicAdd(ws + WS_PART + 2, nb);
            atomicAdd((unsigned int*)(ws + WS_PART + 3), cnt);
        }
    }
}

__global__ __launch_bounds__(256) void k_segmax(const int* __restrict__ eh, const int* __restrict__ ei,
                                                int E, float* __restrict__ ws) {
    int e = blockIdx.x * 256 + threadIdx.x;
    if (e < E) {
        float qe = ws[WS_H12 + (size_t)eh[e] * 12 + 9];
        atomicMax((unsigned int*)(ws + WS_SEGMAX + ei[e]), __float_as_uint(qe));
    }
}

__global__ __launch_bounds__(256) void k_argmin(const int* __restrict__ eh, const int* __restrict__ ei,
                                                int E, float* __restrict__ ws) {
    int e = blockIdx.x * 256 + threadIdx.x;
    if (e < E) {
        float qe = ws[WS_H12 + (size_t)eh[e] * 12 + 9];
        if (qe >= ws[WS_SEGMAX + ei[e]])
            atomicMin((int*)ws + WS_ALPHA + ei[e], eh[e]);
    }
}

__global__ __launch_bounds__(1024) void k_gather(float* __restrict__ ws) {
    const int k = threadIdx.x;
    int a = ((int*)ws)[WS_ALPHA + k];
    a = min(a, NH - 1);
    float4 v0, v1;
    float s8 = 0.0f;
    #pragma unroll
    for (int d0 = 0; d0 < DD; d0 += 4) {
        float4 v = *(const float4*)(ws + WS_OX + (size_t)a * DD + d0);
        *(float4*)(ws + WS_XA + (size_t)k * DD + d0) = v;
        if (d0 == 0) { v0 = v; s8 += v.x*v.x + v.y*v.y + v.z*v.z + v.w*v.w; }
        if (d0 == 4) { v1 = v; s8 += v.x*v.x + v.y*v.y + v.z*v.z + v.w*v.w; }
    }
    *(float4*)(ws + WS_A12 + (size_t)k * 12)     = v0;
    *(float4*)(ws + WS_A12 + (size_t)k * 12 + 4) = v1;
    ws[WS_A12 + (size_t)k * 12 + 8] = 0.5f * (s8 - 1.0f);          // ca
    ws[WS_A12 + (size_t)k * 12 + 9] = ws[WS_H12 + (size_t)a * 12 + 9]; // qa
    float omba = 1.0f - ws[WS_H12 + (size_t)a * 12 + 10];
    for (int off = 32; off > 0; off >>= 1) omba += __shfl_down(omba, off);
    __shared__ float red[16];
    if ((k & 63) == 0) red[k >> 6] = omba;
    __syncthreads();
    if (k == 0) {
        float s = 0.0f;
        for (int i = 0; i < 16; ++i) s += red[i];
        atomicAdd(ws + WS_PART + 4, s);
    }
}

__global__ __launch_bounds__(256) void k_att(const int* __restrict__ eh, const int* __restrict__ ei,
                                             int E, float* __restrict__ ws) {
    const int t = threadIdx.x;
    const int e = blockIdx.x * 256 + t;
    float c = 0.0f;
    if (e < E) {
        const int h = eh[e], k = ei[e];
        const float* a = ws + WS_OX + (size_t)h * DD;
        const float* b = ws + WS_XA + (size_t)k * DD;
        float d2 = 0.0f;
        #pragma unroll
        for (int d0 = 0; d0 < DD; d0 += 4) {
            float4 av = *(const float4*)(a + d0);
            float4 bv = *(const float4*)(b + d0);
            float dx = av.x - bv.x; d2 = fmaf(dx, dx, d2);
            float dy = av.y - bv.y; d2 = fmaf(dy, dy, d2);
            float dz = av.z - bv.z; d2 = fmaf(dz, dz, d2);
            float dw = av.w - bv.w; d2 = fmaf(dw, dw, d2);
        }
        c = ws[WS_H12 + (size_t)h * 12 + 9] * ws[WS_A12 + (size_t)k * 12 + 9] * d2;
    }
    for (int off = 32; off > 0; off >>= 1) c += __shfl_down(c, off);
    __shared__ float red[4];
    if ((t & 63) == 0) red[t >> 6] = c;
    __syncthreads();
    if (t == 0) atomicAdd(ws + WS_PART + 1, red[0] + red[1] + red[2] + red[3]);
}

// v_rep: 512 hits x 64 alphas per block, 2 hits/thread.
// Exact 8-dim lower-bound filter: acc = a8.b8 - |a8|^2/2 - (|b8|^2-1)/2 > 0 <=> d2_8 < 1.
__global__ __launch_bounds__(256, 4) void k_rep(const int* __restrict__ yi, float* __restrict__ ws) {
    __shared__ float al[64 * 12];
    const int t  = threadIdx.x;
    const int bh = blockIdx.x % 96;      // hit tile (512 hits)
    const int bk = blockIdx.x / 96;      // alpha chunk (64 alphas)

    for (int i = t; i < 64 * 12; i += 256)
        al[i] = ws[WS_A12 + (size_t)bk * 64 * 12 + i];
    __syncthreads();

    const int h1 = bh * 512 + t;
    const int h2 = h1 + 256;
    const float4 p0  = *(const float4*)(ws + WS_H12 + (size_t)h1 * 12);
    const float4 p1  = *(const float4*)(ws + WS_H12 + (size_t)h1 * 12 + 4);
    const float2 cq1 = *(const float2*)(ws + WS_H12 + (size_t)h1 * 12 + 8);
    const float4 s0  = *(const float4*)(ws + WS_H12 + (size_t)h2 * 12);
    const float4 s1  = *(const float4*)(ws + WS_H12 + (size_t)h2 * 12 + 4);
    const float2 cq2 = *(const float2*)(ws + WS_H12 + (size_t)h2 * 12 + 8);
    const int yh1 = yi[h1], yh2 = yi[h2];
    float loc = 0.0f;

    #pragma unroll 4
    for (int r = 0; r < 64; ++r) {
        const float4 b0  = *(const float4*)(al + r * 12);
        const float4 b1  = *(const float4*)(al + r * 12 + 4);
        const float2 bcq = *(const float2*)(al + r * 12 + 8);
        float acc1 = -cq1.x - bcq.x;
        acc1 = fmaf(p0.x, b0.x, acc1);
        acc1 = fmaf(p0.y, b0.y, acc1);
        acc1 = fmaf(p0.z, b0.z, acc1);
        acc1 = fmaf(p0.w, b0.w, acc1);
        acc1 = fmaf(p1.x, b1.x, acc1);
        acc1 = fmaf(p1.y, b1.y, acc1);
        acc1 = fmaf(p1.z, b1.z, acc1);
        acc1 = fmaf(p1.w, b1.w, acc1);
        float acc2 = -cq2.x - bcq.x;
        acc2 = fmaf(s0.x, b0.x, acc2);
        acc2 = fmaf(s0.y, b0.y, acc2);
        acc2 = fmaf(s0.z, b0.z, acc2);
        acc2 = fmaf(s0.w, b0.w, acc2);
        acc2 = fmaf(s1.x, b1.x, acc2);
        acc2 = fmaf(s1.y, b1.y, acc2);
        acc2 = fmaf(s1.z, b1.z, acc2);
        acc2 = fmaf(s1.w, b1.w, acc2);
        if (acc1 > 0.0f) {   // rare: d2 over first 8 dims < 1
            const int kg = bk * 64 + r;
            if (yh1 != kg) {
                float d2 = 1.0f - 2.0f * acc1;
                const float* hp = ws + WS_OX + (size_t)h1 * DD;
                const float* ap = ws + WS_XA + (size_t)kg * DD;
                #pragma unroll
                for (int d = 8; d < DD; d += 4) {
                    float4 av = *(const float4*)(hp + d);
                    float4 bv = *(const float4*)(ap + d);
                    float dx = av.x - bv.x; d2 = fmaf(dx, dx, d2);
                    float dy = av.y - bv.y; d2 = fmaf(dy, dy, d2);
                    float dz = av.z - bv.z; d2 = fmaf(dz, dz, d2);
                    float dw = av.w - bv.w; d2 = fmaf(dw, dw, d2);
                }
                float dist = sqrtf(fmaxf(d2, 0.0f) + 1e-12f);
                float hin  = 1.0f - dist;
                if (hin > 0.0f) loc += cq1.y * bcq.y * hin;
            }
        }
        if (acc2 > 0.0f) {
            const int kg = bk * 64 + r;
            if (yh2 != kg) {
                float d2 = 1.0f - 2.0f * acc2;
                const float* hp = ws + WS_OX + (size_t)h2 * DD;
                const float* ap = ws + WS_XA + (size_t)kg * DD;
                #pragma unroll
                for (int d = 8; d < DD; d += 4) {
                    float4 av = *(const float4*)(hp + d);
                    float4 bv = *(const float4*)(ap + d);
                    float dx = av.x - bv.x; d2 = fmaf(dx, dx, d2);
                    float dy = av.y - bv.y; d2 = fmaf(dy, dy, d2);
                    float dz = av.z - bv.z; d2 = fmaf(dz, dz, d2);
                    float dw = av.w - bv.w; d2 = fmaf(dw, dw, d2);
                }
                float dist = sqrtf(fmaxf(d2, 0.0f) + 1e-12f);
                float hin  = 1.0f - dist;
                if (hin > 0.0f) loc += cq2.y * bcq.y * hin;
            }
        }
    }
    for (int off = 32; off > 0; off >>= 1) loc += __shfl_down(loc, off);
    __shared__ float red[4];
    if ((t & 63) == 0) red[t >> 6] = loc;
    __syncthreads();
    if (t == 0) atomicAdd(ws + WS_PART + 0, red[0] + red[1] + red[2] + red[3]);
}

__global__ void k_final(const float* __restrict__ temp, float* __restrict__ ws,
                        float* __restrict__ out) {
    float vrep  = ws[WS_PART + 0];
    float vatt  = ws[WS_PART + 1];
    float nsum  = ws[WS_PART + 2];
    unsigned nn = *(const unsigned int*)(ws + WS_PART + 3);
    float somba = ws[WS_PART + 4];
    float lb = somba * (1.0f / (float)KI) + nsum / (float)(nn < 1u ? 1u : nn);
    float lv = (vatt + vrep) / (float)NH;
    float tv = temp[0];
    out[0] = (lb + lv) * expf(-tv) + tv;
}

extern "C" void kernel_launch(void* const* d_in, const int* in_sizes, int n_in,
                              void* d_out, int out_size, void* d_ws, size_t ws_size,
                              hipStream_t stream) {
    const float* x    = (const float*)d_in[0];
    const float* Wb   = (const float*)d_in[1];
    const float* bb   = (const float*)d_in[2];
    const float* Wc   = (const float*)d_in[3];
    const float* bcrd = (const float*)d_in[4];
    const float* temp = (const float*)d_in[5];
    const int*   yi   = (const int*)d_in[6];
    const int*   ep   = (const int*)d_in[8];
    const int E = in_sizes[8] / 2;
    const int* eh = ep;
    const int* ei = ep + E;
    float* ws  = (float*)d_ws;
    float* out = (float*)d_out;

    k_init<<<(KI + 255) / 256, 256, 0, stream>>>(ws);
    k_gemm<<<NH / 64, 256, 0, stream>>>(x, Wb, bb, Wc, bcrd, yi, ws);
    const int eb = (E + 255) / 256;
    k_segmax<<<eb, 256, 0, stream>>>(eh, ei, E, ws);
    k_argmin<<<eb, 256, 0, stream>>>(eh, ei, E, ws);
    k_gather<<<1, 1024, 0, stream>>>(ws);
    k_att<<<eb, 256, 0, stream>>>(eh, ei, E, ws);
    k_rep<<<96 * 16, 256, 0, stream>>>(yi, ws);
    k_final<<<1, 1, 0, stream>>>(temp, ws, out);
}

// Round 3
// 97.273 us; speedup vs baseline: 1.6524x; 1.2095x over previous
//
#include <hip/hip_runtime.h>
#include <math.h>

#define NH 49152
#define KI 1024
#define DD 32
#define HF 256

// float-index layout in ws
#define WS_PART  0                    // [0]=vrep [1]=vatt [2]=noise_sum [3]=n_noise(u32) [4]=sum(1-beta_a)
#define WS_SEG64 8                    // KI u64 packed (q_bits<<32 | NH-1-h)
#define WS_A12   (WS_SEG64 + 2*KI)    // KI*12: d0..7, ca, qa, pad2
#define WS_H12   (WS_A12 + 12*KI)     // NH*12: d0..7, ch, q, bc, pad
#define WS_XA    (WS_H12 + 12*NH)     // KI*DD full alpha coords
#define WS_OX    (WS_XA + KI*DD)      // NH*DD

__global__ void k_init(float* __restrict__ ws) {
    int i = blockIdx.x * blockDim.x + threadIdx.x;
    if (i < KI) ((unsigned long long*)(ws + WS_SEG64))[i] = 0ull;
    if (i < 8) ws[WS_PART + i] = 0.0f;
}

// GEMM: 128 hits x 33 cols per block. W read via wave-uniform global loads
// (s_load -> SGPR, zero LDS traffic); x staged transposed+swizzled in LDS.
template<bool G3>
__device__ __forceinline__ void chunk_compute(const float (*xs)[128], int l, int kbase, int g,
        const float* __restrict__ Wc, const float* __restrict__ Wb,
        float* acc, float& wA, float& wB) {
    #pragma unroll 8
    for (int kk = 0; kk < 32; ++kk) {
        const int K = ((kk >> 2) & 7) << 2;               // bank swizzle key
        const float2 xv = *(const float2*)(&xs[kk][(2 * l) ^ K]);
        const int krow = kbase + kk;
        const float4 w0 = *(const float4*)(Wc + krow * 32 + g * 8);
        const float4 w1 = *(const float4*)(Wc + krow * 32 + g * 8 + 4);
        acc[0] = fmaf(xv.x, w0.x, acc[0]);   acc[8]  = fmaf(xv.y, w0.x, acc[8]);
        acc[1] = fmaf(xv.x, w0.y, acc[1]);   acc[9]  = fmaf(xv.y, w0.y, acc[9]);
        acc[2] = fmaf(xv.x, w0.z, acc[2]);   acc[10] = fmaf(xv.y, w0.z, acc[10]);
        acc[3] = fmaf(xv.x, w0.w, acc[3]);   acc[11] = fmaf(xv.y, w0.w, acc[11]);
        acc[4] = fmaf(xv.x, w1.x, acc[4]);   acc[12] = fmaf(xv.y, w1.x, acc[12]);
        acc[5] = fmaf(xv.x, w1.y, acc[5]);   acc[13] = fmaf(xv.y, w1.y, acc[13]);
        acc[6] = fmaf(xv.x, w1.z, acc[6]);   acc[14] = fmaf(xv.y, w1.z, acc[14]);
        acc[7] = fmaf(xv.x, w1.w, acc[7]);   acc[15] = fmaf(xv.y, w1.w, acc[15]);
        if (G3) { const float wb = Wb[krow]; wA = fmaf(xv.x, wb, wA); wB = fmaf(xv.y, wb, wB); }
    }
}

__global__ __launch_bounds__(256, 2) void k_gemm(
        const float* __restrict__ x, const float* __restrict__ Wb,
        const float* __restrict__ bb, const float* __restrict__ Wc,
        const float* __restrict__ bcrd, const int* __restrict__ yi,
        float* __restrict__ ws) {
    __shared__ float xsT[2][32][128];
    const int t  = threadIdx.x;
    const int g  = __builtin_amdgcn_readfirstlane(t >> 6);  // wave col-group (SGPR)
    const int l  = t & 63;
    const int h0 = blockIdx.x * 128;

    const int sh = t >> 3;            // staging hit base (0..31)
    const int sq = t & 7;             // staging k-quad
    const int c0 = sh ^ (sq << 2);    // swizzled col
    float4 r0, r1, r2, r3;
#define GLOAD(kc) { \
    const float* xp = x + (size_t)(h0 + sh) * HF + (kc) * 32 + sq * 4; \
    r0 = *(const float4*)(xp); \
    r1 = *(const float4*)(xp + 32 * HF); \
    r2 = *(const float4*)(xp + 64 * HF); \
    r3 = *(const float4*)(xp + 96 * HF); }
#define SSTORE(buf) { \
    float* bp = &xsT[buf][sq * 4][0]; \
    bp[c0]          = r0.x; bp[128 + c0]        = r0.y; bp[256 + c0]        = r0.z; bp[384 + c0]        = r0.w; \
    bp[c0 + 32]     = r1.x; bp[128 + c0 + 32]   = r1.y; bp[256 + c0 + 32]   = r1.z; bp[384 + c0 + 32]   = r1.w; \
    bp[c0 + 64]     = r2.x; bp[128 + c0 + 64]   = r2.y; bp[256 + c0 + 64]   = r2.z; bp[384 + c0 + 64]   = r2.w; \
    bp[c0 + 96]     = r3.x; bp[128 + c0 + 96]   = r3.y; bp[256 + c0 + 96]   = r3.z; bp[384 + c0 + 96]   = r3.w; }

    float acc[16];
    #pragma unroll
    for (int i = 0; i < 16; ++i) acc[i] = 0.0f;
    float wA = 0.0f, wB = 0.0f;

    GLOAD(0);
    SSTORE(0);
    __syncthreads();
    for (int kc = 0; kc < 8; ++kc) {
        if (kc < 7) GLOAD(kc + 1);
        if (g == 3) chunk_compute<true>(xsT[kc & 1], l, kc * 32, g, Wc, Wb, acc, wA, wB);
        else        chunk_compute<false>(xsT[kc & 1], l, kc * 32, g, Wc, Wb, acc, wA, wB);
        __syncthreads();
        if (kc < 7) { SSTORE((kc + 1) & 1); __syncthreads(); }
    }

    const int ha = h0 + 2 * l;
    const float4 bc0 = *(const float4*)(bcrd + g * 8);
    const float4 bc1 = *(const float4*)(bcrd + g * 8 + 4);
    float4 A0 = {acc[0] + bc0.x, acc[1] + bc0.y, acc[2] + bc0.z, acc[3] + bc0.w};
    float4 A1 = {acc[4] + bc1.x, acc[5] + bc1.y, acc[6] + bc1.z, acc[7] + bc1.w};
    float4 B0 = {acc[8] + bc0.x, acc[9] + bc0.y, acc[10] + bc0.z, acc[11] + bc0.w};
    float4 B1 = {acc[12] + bc1.x, acc[13] + bc1.y, acc[14] + bc1.z, acc[15] + bc1.w};
    *(float4*)(ws + WS_OX + (size_t)ha * DD + g * 8)           = A0;
    *(float4*)(ws + WS_OX + (size_t)ha * DD + g * 8 + 4)       = A1;
    *(float4*)(ws + WS_OX + (size_t)(ha + 1) * DD + g * 8)     = B0;
    *(float4*)(ws + WS_OX + (size_t)(ha + 1) * DD + g * 8 + 4) = B1;

    if (g == 0) {   // filter record: dims 0..7 + half-norm
        float sA = A0.x*A0.x + A0.y*A0.y + A0.z*A0.z + A0.w*A0.w
                 + A1.x*A1.x + A1.y*A1.y + A1.z*A1.z + A1.w*A1.w;
        float sB = B0.x*B0.x + B0.y*B0.y + B0.z*B0.z + B0.w*B0.w
                 + B1.x*B1.x + B1.y*B1.y + B1.z*B1.z + B1.w*B1.w;
        *(float4*)(ws + WS_H12 + (size_t)ha * 12)           = A0;
        *(float4*)(ws + WS_H12 + (size_t)ha * 12 + 4)       = A1;
        ws[WS_H12 + (size_t)ha * 12 + 8] = 0.5f * sA;
        *(float4*)(ws + WS_H12 + (size_t)(ha + 1) * 12)     = B0;
        *(float4*)(ws + WS_H12 + (size_t)(ha + 1) * 12 + 4) = B1;
        ws[WS_H12 + (size_t)(ha + 1) * 12 + 8] = 0.5f * sB;
    }
    if (g == 3) {
        const float bb0 = bb[0];
        float zA = wA + bb0, zB = wB + bb0;
        float bA = 1.0f / (1.0f + expf(-zA));
        float bB = 1.0f / (1.0f + expf(-zB));
        float bcA = fminf(fmaxf(bA, 1e-4f), 0.9999f);
        float bcB = fminf(fmaxf(bB, 1e-4f), 0.9999f);
        float atA = atanhf(bcA), atB = atanhf(bcB);
        ws[WS_H12 + (size_t)ha * 12 + 9]        = atA * atA + 0.5f;
        ws[WS_H12 + (size_t)ha * 12 + 10]       = bcA;
        ws[WS_H12 + (size_t)(ha + 1) * 12 + 9]  = atB * atB + 0.5f;
        ws[WS_H12 + (size_t)(ha + 1) * 12 + 10] = bcB;
        int yA = yi[ha], yB = yi[ha + 1];
        float    nb  = ((yA < 0) ? bcA : 0.0f) + ((yB < 0) ? bcB : 0.0f);
        unsigned cnt = (unsigned)(yA < 0) + (unsigned)(yB < 0);
        for (int off = 32; off > 0; off >>= 1) {
            nb  += __shfl_down(nb, off);
            cnt += __shfl_down(cnt, off);
        }
        if (l == 0) {
            atomicAdd(ws + WS_PART + 2, nb);
            atomicAdd((unsigned int*)(ws + WS_PART + 3), cnt);
        }
    }
}

// fused segment argmax: pack (q_bits, NH-1-h) -> one u64 atomicMax.
// among equal q, max(NH-1-h) == min h: identical to reference tie-break.
__global__ __launch_bounds__(256) void k_segmax(const int* __restrict__ eh, const int* __restrict__ ei,
                                                int E, const float* __restrict__ h12,
                                                unsigned long long* __restrict__ seg) {
    int e = blockIdx.x * 256 + threadIdx.x;
    if (e < E) {
        int h = eh[e];
        float q = h12[(size_t)h * 12 + 9];
        unsigned long long pk = ((unsigned long long)__float_as_uint(q) << 32)
                              | (unsigned)(NH - 1 - h);
        atomicMax(seg + ei[e], pk);
    }
}

__global__ __launch_bounds__(256) void k_gather(float* __restrict__ ws) {
    const int k = blockIdx.x * 256 + threadIdx.x;
    unsigned long long pk = ((const unsigned long long*)(ws + WS_SEG64))[k];
    int a = NH - 1 - (int)(unsigned)(pk & 0xffffffffu);
    a = max(0, min(a, NH - 1));
    float4 v0, v1;
    float s8 = 0.0f;
    #pragma unroll
    for (int d0 = 0; d0 < DD; d0 += 4) {
        float4 v = *(const float4*)(ws + WS_OX + (size_t)a * DD + d0);
        *(float4*)(ws + WS_XA + (size_t)k * DD + d0) = v;
        if (d0 == 0) { v0 = v; s8 += v.x*v.x + v.y*v.y + v.z*v.z + v.w*v.w; }
        if (d0 == 4) { v1 = v; s8 += v.x*v.x + v.y*v.y + v.z*v.z + v.w*v.w; }
    }
    *(float4*)(ws + WS_A12 + (size_t)k * 12)     = v0;
    *(float4*)(ws + WS_A12 + (size_t)k * 12 + 4) = v1;
    ws[WS_A12 + (size_t)k * 12 + 8] = 0.5f * (s8 - 1.0f);                    // ca
    ws[WS_A12 + (size_t)k * 12 + 9] = ws[WS_H12 + (size_t)a * 12 + 9];       // qa
    float omba = 1.0f - ws[WS_H12 + (size_t)a * 12 + 10];
    for (int off = 32; off > 0; off >>= 1) omba += __shfl_down(omba, off);
    if ((threadIdx.x & 63) == 0) atomicAdd(ws + WS_PART + 4, omba);
}

__global__ __launch_bounds__(256) void k_att(const int* __restrict__ eh, const int* __restrict__ ei,
                                             int E, float* __restrict__ ws) {
    const int t = threadIdx.x;
    const int e = blockIdx.x * 256 + t;
    float c = 0.0f;
    if (e < E) {
        const int h = eh[e], k = ei[e];
        const float* a = ws + WS_OX + (size_t)h * DD;
        const float* b = ws + WS_XA + (size_t)k * DD;
        float d2 = 0.0f;
        #pragma unroll
        for (int d0 = 0; d0 < DD; d0 += 4) {
            float4 av = *(const float4*)(a + d0);
            float4 bv = *(const float4*)(b + d0);
            float dx = av.x - bv.x; d2 = fmaf(dx, dx, d2);
            float dy = av.y - bv.y; d2 = fmaf(dy, dy, d2);
            float dz = av.z - bv.z; d2 = fmaf(dz, dz, d2);
            float dw = av.w - bv.w; d2 = fmaf(dw, dw, d2);
        }
        c = ws[WS_H12 + (size_t)h * 12 + 9] * ws[WS_A12 + (size_t)k * 12 + 9] * d2;
    }
    for (int off = 32; off > 0; off >>= 1) c += __shfl_down(c, off);
    __shared__ float red[4];
    if ((t & 63) == 0) red[t >> 6] = c;
    __syncthreads();
    if (t == 0) atomicAdd(ws + WS_PART + 1, red[0] + red[1] + red[2] + red[3]);
}

// v_rep: 512 hits x 128 alphas per block; alpha records read via wave-uniform
// global loads (SGPR/scalar-cache broadcast, no LDS). Exact 8-dim filter.
__global__ __launch_bounds__(256, 3) void k_rep(const int* __restrict__ yi,
        const float* __restrict__ a12, const float* __restrict__ h12,
        const float* __restrict__ ox, const float* __restrict__ xa,
        float* __restrict__ part) {
    const int t  = threadIdx.x;
    const int bh = blockIdx.x % 96;
    const int bk = blockIdx.x / 96;
    const int k0 = bk * 128;

    const int h1 = bh * 512 + t;
    const int h2 = h1 + 256;
    const float4 p0  = *(const float4*)(h12 + (size_t)h1 * 12);
    const float4 p1  = *(const float4*)(h12 + (size_t)h1 * 12 + 4);
    const float2 cq1 = *(const float2*)(h12 + (size_t)h1 * 12 + 8);
    const float4 s0  = *(const float4*)(h12 + (size_t)h2 * 12);
    const float4 s1  = *(const float4*)(h12 + (size_t)h2 * 12 + 4);
    const float2 cq2 = *(const float2*)(h12 + (size_t)h2 * 12 + 8);
    const int yh1 = yi[h1], yh2 = yi[h2];
    float loc = 0.0f;

    #pragma unroll 4
    for (int r = 0; r < 128; ++r) {
        const float* ap = a12 + (size_t)(k0 + r) * 12;
        const float4 b0  = *(const float4*)(ap);
        const float4 b1  = *(const float4*)(ap + 4);
        const float2 bcq = *(const float2*)(ap + 8);
        float acc1 = -cq1.x - bcq.x;
        acc1 = fmaf(p0.x, b0.x, acc1);
        acc1 = fmaf(p0.y, b0.y, acc1);
        acc1 = fmaf(p0.z, b0.z, acc1);
        acc1 = fmaf(p0.w, b0.w, acc1);
        acc1 = fmaf(p1.x, b1.x, acc1);
        acc1 = fmaf(p1.y, b1.y, acc1);
        acc1 = fmaf(p1.z, b1.z, acc1);
        acc1 = fmaf(p1.w, b1.w, acc1);
        float acc2 = -cq2.x - bcq.x;
        acc2 = fmaf(s0.x, b0.x, acc2);
        acc2 = fmaf(s0.y, b0.y, acc2);
        acc2 = fmaf(s0.z, b0.z, acc2);
        acc2 = fmaf(s0.w, b0.w, acc2);
        acc2 = fmaf(s1.x, b1.x, acc2);
        acc2 = fmaf(s1.y, b1.y, acc2);
        acc2 = fmaf(s1.z, b1.z, acc2);
        acc2 = fmaf(s1.w, b1.w, acc2);
        if (acc1 > 0.0f) {          // rare: d2 over first 8 dims < 1
            const int kg = k0 + r;
            if (yh1 != kg) {
                float d2 = 1.0f - 2.0f * acc1;
                const float* hp = ox + (size_t)h1 * DD;
                const float* apf = xa + (size_t)kg * DD;
                #pragma unroll
                for (int d = 8; d < DD; d += 4) {
                    float4 av = *(const float4*)(hp + d);
                    float4 bv = *(const float4*)(apf + d);
                    float dx = av.x - bv.x; d2 = fmaf(dx, dx, d2);
                    float dy = av.y - bv.y; d2 = fmaf(dy, dy, d2);
                    float dz = av.z - bv.z; d2 = fmaf(dz, dz, d2);
                    float dw = av.w - bv.w; d2 = fmaf(dw, dw, d2);
                }
                float dist = sqrtf(fmaxf(d2, 0.0f) + 1e-12f);
                float hin  = 1.0f - dist;
                if (hin > 0.0f) loc += cq1.y * bcq.y * hin;
            }
        }
        if (acc2 > 0.0f) {
            const int kg = k0 + r;
            if (yh2 != kg) {
                float d2 = 1.0f - 2.0f * acc2;
                const float* hp = ox + (size_t)h2 * DD;
                const float* apf = xa + (size_t)kg * DD;
                #pragma unroll
                for (int d = 8; d < DD; d += 4) {
                    float4 av = *(const float4*)(hp + d);
                    float4 bv = *(const float4*)(apf + d);
                    float dx = av.x - bv.x; d2 = fmaf(dx, dx, d2);
                    float dy = av.y - bv.y; d2 = fmaf(dy, dy, d2);
                    float dz = av.z - bv.z; d2 = fmaf(dz, dz, d2);
                    float dw = av.w - bv.w; d2 = fmaf(dw, dw, d2);
                }
                float dist = sqrtf(fmaxf(d2, 0.0f) + 1e-12f);
                float hin  = 1.0f - dist;
                if (hin > 0.0f) loc += cq2.y * bcq.y * hin;
            }
        }
    }
    for (int off = 32; off > 0; off >>= 1) loc += __shfl_down(loc, off);
    __shared__ float red[4];
    if ((t & 63) == 0) red[t >> 6] = loc;
    __syncthreads();
    if (t == 0) atomicAdd(part + 0, red[0] + red[1] + red[2] + red[3]);
}

__global__ void k_final(const float* __restrict__ temp, float* __restrict__ ws,
                        float* __restrict__ out) {
    float vrep  = ws[WS_PART + 0];
    float vatt  = ws[WS_PART + 1];
    float nsum  = ws[WS_PART + 2];
    unsigned nn = *(const unsigned int*)(ws + WS_PART + 3);
    float somba = ws[WS_PART + 4];
    float lb = somba * (1.0f / (float)KI) + nsum / (float)(nn < 1u ? 1u : nn);
    float lv = (vatt + vrep) / (float)NH;
    float tv = temp[0];
    out[0] = (lb + lv) * expf(-tv) + tv;
}

extern "C" void kernel_launch(void* const* d_in, const int* in_sizes, int n_in,
                              void* d_out, int out_size, void* d_ws, size_t ws_size,
                              hipStream_t stream) {
    const float* x    = (const float*)d_in[0];
    const float* Wb   = (const float*)d_in[1];
    const float* bb   = (const float*)d_in[2];
    const float* Wc   = (const float*)d_in[3];
    const float* bcrd = (const float*)d_in[4];
    const float* temp = (const float*)d_in[5];
    const int*   yi   = (const int*)d_in[6];
    const int*   ep   = (const int*)d_in[8];
    const int E = in_sizes[8] / 2;
    const int* eh = ep;
    const int* ei = ep + E;
    float* ws  = (float*)d_ws;
    float* out = (float*)d_out;

    k_init<<<4, 256, 0, stream>>>(ws);
    k_gemm<<<NH / 128, 256, 0, stream>>>(x, Wb, bb, Wc, bcrd, yi, ws);
    const int eb = (E + 255) / 256;
    k_segmax<<<eb, 256, 0, stream>>>(eh, ei, E, ws + WS_H12,
                                     (unsigned long long*)(ws + WS_SEG64));
    k_gather<<<KI / 256, 256, 0, stream>>>(ws);
    k_att<<<eb, 256, 0, stream>>>(eh, ei, E, ws);
    k_rep<<<96 * 8, 256, 0, stream>>>(yi, ws + WS_A12, ws + WS_H12,
                                      ws + WS_OX, ws + WS_XA, ws);
    k_final<<<1, 1, 0, stream>>>(temp, ws, out);
}